// Round 9
// baseline (289.059 us; speedup 1.0000x reference)
//
#include <hip/hip_runtime.h>
#include <hip/hip_bf16.h>
#include <cstddef>
#include <cstdint>

#define NN 4096
#define KP 512          // padded K (501 real cols)
#define KTOT 501
#define CHAIN_BLOCKS 64

typedef __attribute__((ext_vector_type(8))) short short8;
typedef __attribute__((ext_vector_type(4))) float f32x4;

#define GLB(p) ((const __attribute__((address_space(1))) void*)(p))
#define LDS(p) ((__attribute__((address_space(3))) void*)(p))

__device__ __forceinline__ float bf2f(unsigned short u) {
    union { unsigned int i; float f; } v; v.i = ((unsigned int)u) << 16; return v.f;
}

__device__ __forceinline__ void split_bf16(float v, unsigned short& h, unsigned short& l) {
    __hip_bfloat16 hb = __float2bfloat16(v);
    __hip_bfloat16 lb = __float2bfloat16(v - __bfloat162float(hb));
    h = *(unsigned short*)&hb;
    l = *(unsigned short*)&lb;
}

// phi(x) = sin(pi x)/(pi x) * exp(-x^2/(2*3.2^2)), phi(0)=1.
__device__ __forceinline__ float phi_eval(float x) {
    if (x == 0.0f) return 1.0f;
    const float PI_F = 3.14159265358979323846f;
    float rn = rintf(x);
    float r  = x - rn;
    float s  = __sinf(PI_F * r);
    if (((int)rn) & 1) s = -s;
    float e  = __expf(-x * x * (1.0f / 20.48f));
    return __fdividef(s * e, PI_F * x);
}

__device__ __forceinline__ void col_to_level(int col, int& l, int& off) {
    if      (col < 17)  { l = 0; off = 0;   }
    else if (col < 50)  { l = 1; off = 17;  }
    else if (col < 115) { l = 2; off = 50;  }
    else                { l = (col < 244) ? 3 : 4; off = (col < 244) ? 115 : 244; }
}

// ---- coherent WRITE-THROUGH store for cross-phase data ------------------
// sc0 sc1 store: reaches the fabric coherence point; later cached loads
// (which never cached the stale line) see the value. Verified r5/r7.
__device__ __forceinline__ void st_coh(float* p, float v) {
    __hip_atomic_store(p, v, __ATOMIC_RELAXED, __HIP_MEMORY_SCOPE_AGENT);
}

// ---- tree grid barrier, 64 participants ---------------------------------
// r7 postmortem: barrier cost tracked TOTAL participants (~40ns/atomic at
// the fabric), not line layout (tree-256 ~= flat-256). Lever = fewer
// participants: 64 blocks, 8 groups x 8. Busy-spin s_sleep(1): each block
// is alone on its CU (64 blocks / 256 CUs), so spinning steals nothing.
#define BAR_GEN    0
#define BAR_ROOT   16
#define BAR_GRP(g) (32 + (g) * 16)
#define BAR_INTS   (32 + 8 * 16)

__device__ __forceinline__ void gridbar(int* bar, int phase) {
    __syncthreads();
    if (threadIdx.x == 0) {
        asm volatile("s_waitcnt vmcnt(0) lgkmcnt(0)" ::: "memory");
        const int g = blockIdx.x >> 3;                      // 8 blocks/group, 8 groups
        int t = __hip_atomic_fetch_add(&bar[BAR_GRP(g)], 1, __ATOMIC_RELAXED, __HIP_MEMORY_SCOPE_AGENT);
        if (t == 8 * phase - 1) {                           // last of group this phase
            int r = __hip_atomic_fetch_add(&bar[BAR_ROOT], 1, __ATOMIC_RELAXED, __HIP_MEMORY_SCOPE_AGENT);
            if (r == 8 * phase - 1) {                       // last group
                __hip_atomic_store(&bar[BAR_GEN], phase, __ATOMIC_RELAXED, __HIP_MEMORY_SCOPE_AGENT);
            }
        }
        long guard = 0;
        while (__hip_atomic_load(&bar[BAR_GEN], __ATOMIC_RELAXED, __HIP_MEMORY_SCOPE_AGENT) < phase) {
            __builtin_amdgcn_s_sleep(1);
            if (++guard > (1L << 22)) break;                // hang-guard: fail test, not harness
        }
        asm volatile("" ::: "memory");
    }
    __syncthreads();
}

// ---- kernel 1: fused prep -----------------------------------------------
// blocks [0,1002): nearest; [1002,2026): phi tables (split-bf16 direct);
// [2026,2058): zero Ch/Cl (contiguous 1 MB). Block 0 also zeros barrier.
__global__ __launch_bounds__(256) void fused_pre(const float* __restrict__ xc,
                                                 const float* __restrict__ xr,
                                                 unsigned short* __restrict__ PCh,
                                                 unsigned short* __restrict__ PCl,
                                                 unsigned short* __restrict__ PRh,
                                                 unsigned short* __restrict__ PRl,
                                                 unsigned short* __restrict__ Ch,
                                                 int* __restrict__ idxAll,
                                                 int* __restrict__ bar) {
    __shared__ float sv[256];
    __shared__ int   si[256];
    const int b = blockIdx.x;
    const int tid = threadIdx.x;
    if (b == 0) {
        for (int z = tid; z < BAR_INTS; z += 256) bar[z] = 0;
    }
    if (b < 2 * KTOT) {
        int side = (b >= KTOT);
        int col  = side ? b - KTOT : b;
        const float* x = side ? xr : xc;
        int l, off; col_to_level(col, l, off);
        int s = 8 << l;
        float target = (float)(col - off - s) / (float)s;
        float best = 1e30f; int bidx = 0;
        for (int n = tid; n < NN; n += 256) {
            float d = fabsf(x[n] - target);
            if (d < best) { best = d; bidx = n; }
        }
        sv[tid] = best; si[tid] = bidx;
        __syncthreads();
        for (int w = 128; w > 0; w >>= 1) {
            if (tid < w) {
                float ov = sv[tid + w]; int oi = si[tid + w];
                if (ov < sv[tid] || (ov == sv[tid] && oi < si[tid])) { sv[tid] = ov; si[tid] = oi; }
            }
            __syncthreads();
        }
        if (tid == 0) idxAll[b] = si[0];
    } else if (b < 2026) {
        const int i0 = (b - 1002) * 2048 + tid;
        #pragma unroll
        for (int j = 0; j < 8; ++j) {
            int i = i0 + j * 256;
            int n = i >> 9, col = i & 511;
            float pc = 0.f, pr = 0.f;
            if (col < KTOT) {
                int l, off; col_to_level(col, l, off);
                int s = 8 << l;
                float fo = (float)(col - off - s);
                float fs = (float)s;
                pc = phi_eval(fs * xc[n] - fo);
                pr = phi_eval(fs * xr[n] - fo);
            }
            unsigned short h, l2;
            split_bf16(pc, h, l2); PCh[i] = h; PCl[i] = l2;
            split_bf16(pr, h, l2); PRh[i] = h; PRl[i] = l2;
        }
    } else {
        // zero Ch+Cl: contiguous 2*KP*KP ushorts = 64K uint4
        uint4* z = (uint4*)Ch;
        const int g0 = (b - 2026) * 256 + tid;
        #pragma unroll
        for (int j = 0; j < 8; ++j) {
            int g = g0 + j * 8192;
            z[g] = make_uint4(0u, 0u, 0u, 0u);
        }
    }
}

// ---- fused serial chain: plain cached vectorized loads, coherent stores -

__device__ __forceinline__ void do_build(int T, int OFF,
                                         const float* __restrict__ img,
                                         const int* __restrict__ idxAll,
                                         const float* __restrict__ Usm,
                                         const unsigned short* __restrict__ PRh,
                                         const unsigned short* __restrict__ PRl,
                                         float* __restrict__ CdT,
                                         unsigned short* __restrict__ Ch,
                                         unsigned short* __restrict__ Cl,
                                         int gid, int gsize) {
    const int tot = T * T;
    for (int i = gid; i < tot; i += gsize) {
        int p = i / T, q = i - p * T;
        int ip = idxAll[OFF + p];
        int iq = idxAll[KTOT + OFF + q];
        float f = img[(size_t)ip * NN + iq];
        float val;
        if (OFF == 0) {
            val = f;
        } else {
            const float* u = Usm + (size_t)(OFF + p) * KP;   // k from 0, 16B aligned
            const unsigned short* ph = PRh + (size_t)iq * KP;
            const unsigned short* pl = PRl + (size_t)iq * KP;
            float s0 = 0.f, s1 = 0.f, s2 = 0.f, s3 = 0.f;
            int k = 0;
            #pragma unroll 4
            for (; k + 4 <= OFF; k += 4) {
                ushort4 h4 = *(const ushort4*)(ph + k);
                ushort4 l4 = *(const ushort4*)(pl + k);
                float4  b4 = *(const float4*)(u + k);
                s0 += (bf2f(h4.x) + bf2f(l4.x)) * b4.x;
                s1 += (bf2f(h4.y) + bf2f(l4.y)) * b4.y;
                s2 += (bf2f(h4.z) + bf2f(l4.z)) * b4.z;
                s3 += (bf2f(h4.w) + bf2f(l4.w)) * b4.w;
            }
            float uu = (s0 + s1) + (s2 + s3);
            for (; k < OFF; ++k) uu += (bf2f(ph[k]) + bf2f(pl[k])) * u[k];
            float d = f - uu;
            val = (fabsf(d) > 0.01f) ? d : 0.0f;
        }
        size_t o = (size_t)(OFF + q) * KP + (OFF + p);       // dense transposed
        st_coh(&CdT[o], val);
        unsigned short h, l;
        split_bf16(val, h, l);
        Ch[o] = h; Cl[o] = l;
    }
}

__device__ __forceinline__ void do_update(int T, int OFF,
                                          const unsigned short* __restrict__ PCh,
                                          const unsigned short* __restrict__ PCl,
                                          const int* __restrict__ idxAll,
                                          const float* __restrict__ CdT,
                                          float* __restrict__ Usm,
                                          int gid, int gsize) {
    // Only rows r >= OFF+T are read by later build phases; skip unread rows.
    const int R0 = OFF + T;
    const int tot = (KTOT - R0) * T;
    const int HEAD = (4 - (OFF & 3)) & 3;
    for (int i = gid; i < tot; i += gsize) {
        int r = R0 + i / T, t = i - (i / T) * T;
        const unsigned short* ah = PCh + (size_t)idxAll[r] * KP + OFF;
        const unsigned short* al = PCl + (size_t)idxAll[r] * KP + OFF;
        const float* b = CdT + (size_t)(OFF + t) * KP + OFF;
        float s = 0.f;
        int k = 0;
        for (; k < HEAD; ++k) s += (bf2f(ah[k]) + bf2f(al[k])) * b[k];
        float s0 = 0.f, s1 = 0.f, s2 = 0.f, s3 = 0.f;
        #pragma unroll 4
        for (; k + 4 <= T; k += 4) {
            ushort4 h4 = *(const ushort4*)(ah + k);
            ushort4 l4 = *(const ushort4*)(al + k);
            float4  b4 = *(const float4*)(b + k);
            s0 += (bf2f(h4.x) + bf2f(l4.x)) * b4.x;
            s1 += (bf2f(h4.y) + bf2f(l4.y)) * b4.y;
            s2 += (bf2f(h4.z) + bf2f(l4.z)) * b4.z;
            s3 += (bf2f(h4.w) + bf2f(l4.w)) * b4.w;
        }
        s += (s0 + s1) + (s2 + s3);
        for (; k < T; ++k) s += (bf2f(ah[k]) + bf2f(al[k])) * b[k];
        st_coh(&Usm[(size_t)r * KP + OFF + t], s);
    }
}

__global__ __launch_bounds__(256) void chain_fused(const float* __restrict__ img,
                                                   const int* __restrict__ idxAll,
                                                   float* __restrict__ Usm,
                                                   const unsigned short* __restrict__ PRh,
                                                   const unsigned short* __restrict__ PRl,
                                                   float* __restrict__ CdT,
                                                   unsigned short* __restrict__ Ch,
                                                   unsigned short* __restrict__ Cl,
                                                   const unsigned short* __restrict__ PCh,
                                                   const unsigned short* __restrict__ PCl,
                                                   int* __restrict__ bar) {
    const int gsize = gridDim.x * 256;
    const int gid   = blockIdx.x * 256 + threadIdx.x;

    do_build(17, 0, img, idxAll, Usm, PRh, PRl, CdT, Ch, Cl, gid, gsize);
    gridbar(bar, 1);
    do_update(17, 0, PCh, PCl, idxAll, CdT, Usm, gid, gsize);
    gridbar(bar, 2);
    do_build(33, 17, img, idxAll, Usm, PRh, PRl, CdT, Ch, Cl, gid, gsize);
    gridbar(bar, 3);
    do_update(33, 17, PCh, PCl, idxAll, CdT, Usm, gid, gsize);
    gridbar(bar, 4);
    do_build(65, 50, img, idxAll, Usm, PRh, PRl, CdT, Ch, Cl, gid, gsize);
    gridbar(bar, 5);
    do_update(65, 50, PCh, PCl, idxAll, CdT, Usm, gid, gsize);
    gridbar(bar, 6);
    do_build(129, 115, img, idxAll, Usm, PRh, PRl, CdT, Ch, Cl, gid, gsize);
    gridbar(bar, 7);
    do_update(129, 115, PCh, PCl, idxAll, CdT, Usm, gid, gsize);
    gridbar(bar, 8);
    do_build(257, 244, img, idxAll, Usm, PRh, PRl, CdT, Ch, Cl, gid, gsize);
}

// ---- MFMA GEMMs: 2-phase prefetch pipeline + swizzled LDS ---------------
// Swizzle (rule 21): linear gload_lds dest + pre-swizzled GLOBAL source +
// same-XOR read. Conflict-free ds_read_b128 (verified r1: 1.93M -> 0).
// Pipeline: stage chunk t+1, ds_read+MFMA chunk t, one syncthreads/iter.
#define GEMM_BODY(Ahi_, Alo_, Bhi_, Blo_, XARR_, XBASE_, BMASK_)                       \
    __shared__ short As_h[2][128][32];                                                 \
    __shared__ short As_l[2][128][32];                                                 \
    __shared__ short Bs_h[2][128][32];                                                 \
    __shared__ short Bs_l[2][128][32];                                                 \
    const int tid  = threadIdx.x;                                                      \
    const int lane = tid & 63;                                                         \
    const int wave = tid >> 6;                                                         \
    const int wr   = wave >> 1;                                                        \
    const int wc   = wave & 1;                                                         \
    const int row0 = blockIdx.y * 128;                                                 \
    const int col0 = blockIdx.x * 128;                                                 \
    int list[16]; int nch = 0;                                                         \
    {                                                                                  \
        float xmn = XARR_[XBASE_];                                                     \
        float xmx = XARR_[(XBASE_) + 127];                                             \
        int mask = 0;                                                                  \
        const int off_[5] = {0, 17, 50, 115, 244};                                     \
        _Pragma("unroll")                                                              \
        for (int l = 0; l < 5; ++l) {                                                  \
            int s_ = 8 << l;                                                           \
            int clo = off_[l] + s_ + (int)floorf(s_ * xmn - 12.5f);                    \
            int chi = off_[l] + s_ + (int)ceilf (s_ * xmx + 12.5f);                    \
            if (clo < off_[l]) clo = off_[l];                                          \
            if (chi > off_[l] + 2 * s_) chi = off_[l] + 2 * s_;                        \
            for (int c = clo >> 5; c <= (chi >> 5); ++c) mask |= 1 << c;               \
        }                                                                              \
        mask &= (BMASK_);                                                              \
        for (int c = 0; c < 16; ++c) if ((mask >> c) & 1) list[nch++] = c;             \
    }                                                                                  \
    f32x4 acc[4][4];                                                                   \
    _Pragma("unroll")                                                                  \
    for (int i = 0; i < 4; ++i)                                                        \
        _Pragma("unroll")                                                              \
        for (int j = 0; j < 4; ++j) acc[i][j] = (f32x4){0.f, 0.f, 0.f, 0.f};           \
    const int srow = lane >> 2;                                                        \
    const int scol = ((lane & 3) ^ ((lane >> 3) & 3)) * 8;  /* pre-swizzled source */  \
    auto stage_ = [&](int bb, int k0) {                                                \
        _Pragma("unroll")                                                              \
        for (int s = 0; s < 2; ++s) {                                                  \
            const int rseg = wave * 32 + s * 16;                                       \
            const size_t ga = (size_t)(row0 + rseg + srow) * KP + k0 + scol;           \
            const size_t gb = (size_t)(col0 + rseg + srow) * KP + k0 + scol;           \
            __builtin_amdgcn_global_load_lds(GLB(Ahi_ + ga), LDS(&As_h[bb][rseg][0]), 16, 0, 0); \
            __builtin_amdgcn_global_load_lds(GLB(Alo_ + ga), LDS(&As_l[bb][rseg][0]), 16, 0, 0); \
            __builtin_amdgcn_global_load_lds(GLB(Bhi_ + gb), LDS(&Bs_h[bb][rseg][0]), 16, 0, 0); \
            __builtin_amdgcn_global_load_lds(GLB(Blo_ + gb), LDS(&Bs_l[bb][rseg][0]), 16, 0, 0); \
        }                                                                              \
    };                                                                                 \
    const int kbsw = 8 * ((lane >> 4) ^ ((lane >> 1) & 3)); /* swizzled read slot */   \
    if (nch > 0) stage_(0, list[0] * 32);                                              \
    __syncthreads();                                                                   \
    for (int ic = 0; ic < nch; ++ic) {                                                 \
        const int cb = ic & 1;                                                         \
        if (ic + 1 < nch) stage_(cb ^ 1, list[ic + 1] * 32);                           \
        short8 ah[4], al[4], bh[4], bl[4];                                             \
        _Pragma("unroll")                                                              \
        for (int mb = 0; mb < 4; ++mb) {                                               \
            const int rr = wr * 64 + mb * 16 + (lane & 15);                            \
            ah[mb] = *(const short8*)&As_h[cb][rr][kbsw];                              \
            al[mb] = *(const short8*)&As_l[cb][rr][kbsw];                              \
        }                                                                              \
        _Pragma("unroll")                                                              \
        for (int nb = 0; nb < 4; ++nb) {                                               \
            const int cc = wc * 64 + nb * 16 + (lane & 15);                            \
            bh[nb] = *(const short8*)&Bs_h[cb][cc][kbsw];                              \
            bl[nb] = *(const short8*)&Bs_l[cb][cc][kbsw];                              \
        }                                                                              \
        _Pragma("unroll")                                                              \
        for (int mb = 0; mb < 4; ++mb)                                                 \
            _Pragma("unroll")                                                          \
            for (int nb = 0; nb < 4; ++nb) {                                           \
                acc[mb][nb] = __builtin_amdgcn_mfma_f32_16x16x32_bf16(ah[mb], bh[nb], acc[mb][nb], 0, 0, 0); \
                acc[mb][nb] = __builtin_amdgcn_mfma_f32_16x16x32_bf16(ah[mb], bl[nb], acc[mb][nb], 0, 0, 0); \
                acc[mb][nb] = __builtin_amdgcn_mfma_f32_16x16x32_bf16(al[mb], bh[nb], acc[mb][nb], 0, 0, 0); \
            }                                                                          \
        __syncthreads();                                                               \
    }                                                                                  \
    const int orow = (lane >> 4) * 4;                                                  \
    const int ocol = lane & 15;

// gemm2: out = U x PhiR^T, fp32 out; B-side (xr) k-sparsity from col-tile.
__global__ __launch_bounds__(256) void gemm_mfma_f32out(const short* __restrict__ Ahi,
                                                        const short* __restrict__ Alo,
                                                        const short* __restrict__ Bhi,
                                                        const short* __restrict__ Blo,
                                                        const float* __restrict__ xr,
                                                        float* __restrict__ out) {
    GEMM_BODY(Ahi, Alo, Bhi, Blo, xr, blockIdx.x * 128, 0xFFFF)
    #pragma unroll
    for (int mb = 0; mb < 4; ++mb)
        #pragma unroll
        for (int nb = 0; nb < 4; ++nb) {
            const int col = col0 + wc * 64 + nb * 16 + ocol;
            #pragma unroll
            for (int reg = 0; reg < 4; ++reg) {
                const int row = row0 + wr * 64 + mb * 16 + orow + reg;
                out[(size_t)row * NN + col] = acc[mb][nb][reg];
            }
        }
}

// gemm1: U = PhiC x C^T, split-bf16 out; A-side (xc) sparsity AND static
// block-diagonal B mask by col-tile.
__global__ __launch_bounds__(256) void gemm_mfma_splitout(const short* __restrict__ Ahi,
                                                          const short* __restrict__ Alo,
                                                          const short* __restrict__ Bhi,
                                                          const short* __restrict__ Blo,
                                                          const float* __restrict__ xc,
                                                          unsigned short* __restrict__ Oh,
                                                          unsigned short* __restrict__ Ol) {
    const int bmask_tab[4] = {0x00FF, 0xFFF8, 0xFF80, 0xFF80};
    const int bm = bmask_tab[blockIdx.x];
    GEMM_BODY(Ahi, Alo, Bhi, Blo, xc, blockIdx.y * 128, bm)
    #pragma unroll
    for (int mb = 0; mb < 4; ++mb)
        #pragma unroll
        for (int nb = 0; nb < 4; ++nb) {
            const int col = col0 + wc * 64 + nb * 16 + ocol;
            #pragma unroll
            for (int reg = 0; reg < 4; ++reg) {
                const int row = row0 + wr * 64 + mb * 16 + orow + reg;
                unsigned short h, l;
                split_bf16(acc[mb][nb][reg], h, l);
                Oh[(size_t)row * KP + col] = h;
                Ol[(size_t)row * KP + col] = l;
            }
        }
}

extern "C" void kernel_launch(void* const* d_in, const int* in_sizes, int n_in,
                              void* d_out, int out_size, void* d_ws, size_t ws_size,
                              hipStream_t stream) {
    const float* img = (const float*)d_in[0];
    const float* xc  = (const float*)d_in[1];
    const float* xr  = (const float*)d_in[2];
    float* out = (float*)d_out;

    const size_t M2 = (size_t)NN * KP;
    // ws: PCh|PCl|PRh|PRl|Uh|Ul (6 x 4MB bf16) | Usm(1MB) | CdT(1MB) | Ch|Cl(1MB) | idx | bar
    unsigned short* PCh = (unsigned short*)d_ws;
    unsigned short* PCl = PCh + M2;
    unsigned short* PRh = PCl + M2;
    unsigned short* PRl = PRh + M2;
    unsigned short* Uh  = PRl + M2;
    unsigned short* Ul  = Uh + M2;
    float* Usm = (float*)(Ul + M2);
    float* CdT = Usm + (size_t)KP * KP;
    unsigned short* Ch = (unsigned short*)(CdT + (size_t)KP * KP);
    unsigned short* Cl = Ch + (size_t)KP * KP;
    int* idxAll = (int*)(Cl + (size_t)KP * KP);
    int* bar = idxAll + 1024;      // BAR_INTS ints, after idxAll (2*KTOT used)

    // 1: prep (nearest + split phi tables + zero Ch/Cl + barrier init)
    fused_pre<<<dim3(2058), 256, 0, stream>>>(xc, xr, PCh, PCl, PRh, PRl, Ch, idxAll, bar);

    // 2: fused serial chain — 64 blocks (fewer barrier participants),
    // cached vectorized loads + coherent stores + tree barrier.
    chain_fused<<<dim3(CHAIN_BLOCKS), 256, 0, stream>>>(
        img, idxAll, Usm, PRh, PRl, CdT, Ch, Cl, PCh, PCl, bar);

    // 3: gemm1  U = PhiC x C^T (split-bf16 out)
    gemm_mfma_splitout<<<dim3(KP / 128, NN / 128), 256, 0, stream>>>(
        (const short*)PCh, (const short*)PCl, (const short*)Ch, (const short*)Cl, xc, Uh, Ul);
    // 4: gemm2  out = U x PhiR^T
    gemm_mfma_f32out<<<dim3(NN / 128, NN / 128), 256, 0, stream>>>(
        (const short*)Uh, (const short*)Ul, (const short*)PRh, (const short*)PRl, xr, out);
}

// Round 11
// 220.556 us; speedup vs baseline: 1.3106x; 1.3106x over previous
//
#include <hip/hip_runtime.h>
#include <hip/hip_bf16.h>
#include <cstddef>
#include <cstdint>

#define NN 4096
#define KP 512          // padded K (501 real cols)
#define KTOT 501

typedef __attribute__((ext_vector_type(8))) short short8;
typedef __attribute__((ext_vector_type(4))) float f32x4;

#define GLB(p) ((const __attribute__((address_space(1))) void*)(p))
#define LDS(p) ((__attribute__((address_space(3))) void*)(p))

__device__ __forceinline__ float bf2f(unsigned short u) {
    union { unsigned int i; float f; } v; v.i = ((unsigned int)u) << 16; return v.f;
}

__device__ __forceinline__ void split_bf16(float v, unsigned short& h, unsigned short& l) {
    __hip_bfloat16 hb = __float2bfloat16(v);
    __hip_bfloat16 lb = __float2bfloat16(v - __bfloat162float(hb));
    h = *(unsigned short*)&hb;
    l = *(unsigned short*)&lb;
}

// phi(x) = sin(pi x)/(pi x) * exp(-x^2/(2*3.2^2)), phi(0)=1.
__device__ __forceinline__ float phi_eval(float x) {
    if (x == 0.0f) return 1.0f;
    const float PI_F = 3.14159265358979323846f;
    float rn = rintf(x);
    float r  = x - rn;
    float s  = __sinf(PI_F * r);
    if (((int)rn) & 1) s = -s;
    float e  = __expf(-x * x * (1.0f / 20.48f));
    return __fdividef(s * e, PI_F * x);
}

__device__ __forceinline__ void col_to_level(int col, int& l, int& off) {
    if      (col < 17)  { l = 0; off = 0;   }
    else if (col < 50)  { l = 1; off = 17;  }
    else if (col < 115) { l = 2; off = 50;  }
    else                { l = (col < 244) ? 3 : 4; off = (col < 244) ? 115 : 244; }
}

// ---- kernel 1: fused prep -----------------------------------------------
// blocks [0,1002): nearest; [1002,2026): phi tables (split-bf16 direct);
// [2026,2058): zero Ch/Cl (contiguous 1 MB).
__global__ __launch_bounds__(256) void fused_pre(const float* __restrict__ xc,
                                                 const float* __restrict__ xr,
                                                 unsigned short* __restrict__ PCh,
                                                 unsigned short* __restrict__ PCl,
                                                 unsigned short* __restrict__ PRh,
                                                 unsigned short* __restrict__ PRl,
                                                 unsigned short* __restrict__ Ch,
                                                 int* __restrict__ idxAll) {
    __shared__ float sv[256];
    __shared__ int   si[256];
    const int b = blockIdx.x;
    const int tid = threadIdx.x;
    if (b < 2 * KTOT) {
        int side = (b >= KTOT);
        int col  = side ? b - KTOT : b;
        const float* x = side ? xr : xc;
        int l, off; col_to_level(col, l, off);
        int s = 8 << l;
        float target = (float)(col - off - s) / (float)s;
        float best = 1e30f; int bidx = 0;
        for (int n = tid; n < NN; n += 256) {
            float d = fabsf(x[n] - target);
            if (d < best) { best = d; bidx = n; }
        }
        sv[tid] = best; si[tid] = bidx;
        __syncthreads();
        for (int w = 128; w > 0; w >>= 1) {
            if (tid < w) {
                float ov = sv[tid + w]; int oi = si[tid + w];
                if (ov < sv[tid] || (ov == sv[tid] && oi < si[tid])) { sv[tid] = ov; si[tid] = oi; }
            }
            __syncthreads();
        }
        if (tid == 0) idxAll[b] = si[0];
    } else if (b < 2026) {
        const int i0 = (b - 1002) * 2048 + tid;
        #pragma unroll
        for (int j = 0; j < 8; ++j) {
            int i = i0 + j * 256;
            int n = i >> 9, col = i & 511;
            float pc = 0.f, pr = 0.f;
            if (col < KTOT) {
                int l, off; col_to_level(col, l, off);
                int s = 8 << l;
                float fo = (float)(col - off - s);
                float fs = (float)s;
                pc = phi_eval(fs * xc[n] - fo);
                pr = phi_eval(fs * xr[n] - fo);
            }
            unsigned short h, l2;
            split_bf16(pc, h, l2); PCh[i] = h; PCl[i] = l2;
            split_bf16(pr, h, l2); PRh[i] = h; PRl[i] = l2;
        }
    } else {
        // zero Ch+Cl: contiguous 2*KP*KP ushorts = 64K uint4
        uint4* z = (uint4*)Ch;
        const int g0 = (b - 2026) * 256 + tid;
        #pragma unroll
        for (int j = 0; j < 8; ++j) {
            int g = g0 + j * 8192;
            z[g] = make_uint4(0u, 0u, 0u, 0u);
        }
    }
}

// ---- folded build+update, one block per column t ------------------------
// Key dependency fact (from the fused-chain analysis r2-r9): update(r,t)
// reads ONLY build column q=t, and that column is computable by one block
// (iq fixed, loop over p). So per level: block t computes its column into
// LDS vals[], __syncthreads, then all updates for column t. No cross-block
// dependency -> no grid barrier, no coherent stores, CdT eliminated
// (column lives in LDS). Arithmetic is bit-identical to the split
// build_k/update_k pair (same dot structure, same HEAD peel).
template<int T, int OFF>
__global__ __launch_bounds__(256) void fold_k(const float* __restrict__ img,
                                              const int* __restrict__ idxAll,
                                              float* __restrict__ Usm,
                                              const unsigned short* __restrict__ PRh,
                                              const unsigned short* __restrict__ PRl,
                                              const unsigned short* __restrict__ PCh,
                                              const unsigned short* __restrict__ PCl,
                                              unsigned short* __restrict__ Ch,
                                              unsigned short* __restrict__ Cl) {
    __shared__ float vals[T];
    const int t   = blockIdx.x;
    const int tid = threadIdx.x;
    const int iq  = idxAll[KTOT + OFF + t];

    // build column q=t: val(p,t) for p in [0,T)
    for (int p = tid; p < T; p += 256) {
        int ip = idxAll[OFF + p];
        float f = img[(size_t)ip * NN + iq];
        float val;
        if (OFF == 0) {
            val = f;
        } else {
            const float* u = Usm + (size_t)(OFF + p) * KP;   // k from 0, 16B aligned
            const unsigned short* ph = PRh + (size_t)iq * KP;
            const unsigned short* pl = PRl + (size_t)iq * KP;
            float s0 = 0.f, s1 = 0.f, s2 = 0.f, s3 = 0.f;
            int k = 0;
            #pragma unroll 4
            for (; k + 4 <= OFF; k += 4) {
                ushort4 h4 = *(const ushort4*)(ph + k);
                ushort4 l4 = *(const ushort4*)(pl + k);
                float4  b4 = *(const float4*)(u + k);
                s0 += (bf2f(h4.x) + bf2f(l4.x)) * b4.x;
                s1 += (bf2f(h4.y) + bf2f(l4.y)) * b4.y;
                s2 += (bf2f(h4.z) + bf2f(l4.z)) * b4.z;
                s3 += (bf2f(h4.w) + bf2f(l4.w)) * b4.w;
            }
            float uu = (s0 + s1) + (s2 + s3);
            for (; k < OFF; ++k) uu += (bf2f(ph[k]) + bf2f(pl[k])) * u[k];
            float d = f - uu;
            val = (fabsf(d) > 0.01f) ? d : 0.0f;
        }
        vals[p] = val;
        size_t o = (size_t)(OFF + t) * KP + (OFF + p);       // dense transposed
        unsigned short h, l;
        split_bf16(val, h, l);
        Ch[o] = h; Cl[o] = l;
    }
    __syncthreads();

    // update column OFF+t of Usm for rows r >= OFF+T (only those are read
    // by later build phases; verified r5).
    constexpr int R0 = OFF + T;
    constexpr int HEAD = (4 - (OFF & 3)) & 3;
    for (int r = R0 + tid; r < KTOT; r += 256) {
        const unsigned short* ah = PCh + (size_t)idxAll[r] * KP + OFF;
        const unsigned short* al = PCl + (size_t)idxAll[r] * KP + OFF;
        float s = 0.f;
        int k = 0;
        #pragma unroll
        for (; k < HEAD; ++k) s += (bf2f(ah[k]) + bf2f(al[k])) * vals[k];
        float s0 = 0.f, s1 = 0.f, s2 = 0.f, s3 = 0.f;
        #pragma unroll 4
        for (; k + 4 <= T; k += 4) {
            ushort4 h4 = *(const ushort4*)(ah + k);
            ushort4 l4 = *(const ushort4*)(al + k);
            s0 += (bf2f(h4.x) + bf2f(l4.x)) * vals[k];
            s1 += (bf2f(h4.y) + bf2f(l4.y)) * vals[k + 1];
            s2 += (bf2f(h4.z) + bf2f(l4.z)) * vals[k + 2];
            s3 += (bf2f(h4.w) + bf2f(l4.w)) * vals[k + 3];
        }
        s += (s0 + s1) + (s2 + s3);
        for (; k < T; ++k) s += (bf2f(ah[k]) + bf2f(al[k])) * vals[k];
        Usm[(size_t)r * KP + OFF + t] = s;
    }
}

// ---- final level: build-only (no update after), Ch/Cl only --------------
__global__ __launch_bounds__(256) void build_last(const float* __restrict__ img,
                                                  const int* __restrict__ idxAll,
                                                  const float* __restrict__ Usm,
                                                  const unsigned short* __restrict__ PRh,
                                                  const unsigned short* __restrict__ PRl,
                                                  unsigned short* __restrict__ Ch,
                                                  unsigned short* __restrict__ Cl) {
    constexpr int T = 257, OFF = 244;
    int i = blockIdx.x * 256 + threadIdx.x;
    if (i >= T * T) return;
    int p = i / T, q = i - p * T;
    int ip = idxAll[OFF + p];
    int iq = idxAll[KTOT + OFF + q];
    float f = img[(size_t)ip * NN + iq];
    const float* u = Usm + (size_t)(OFF + p) * KP;
    const unsigned short* ph = PRh + (size_t)iq * KP;
    const unsigned short* pl = PRl + (size_t)iq * KP;
    float s0 = 0.f, s1 = 0.f, s2 = 0.f, s3 = 0.f;
    int k = 0;
    #pragma unroll 4
    for (; k + 4 <= OFF; k += 4) {
        ushort4 h4 = *(const ushort4*)(ph + k);
        ushort4 l4 = *(const ushort4*)(pl + k);
        float4  b4 = *(const float4*)(u + k);
        s0 += (bf2f(h4.x) + bf2f(l4.x)) * b4.x;
        s1 += (bf2f(h4.y) + bf2f(l4.y)) * b4.y;
        s2 += (bf2f(h4.z) + bf2f(l4.z)) * b4.z;
        s3 += (bf2f(h4.w) + bf2f(l4.w)) * b4.w;
    }
    float uu = (s0 + s1) + (s2 + s3);
    for (; k < OFF; ++k) uu += (bf2f(ph[k]) + bf2f(pl[k])) * u[k];
    float d = f - uu;
    float val = (fabsf(d) > 0.01f) ? d : 0.0f;
    size_t o = (size_t)(OFF + q) * KP + (OFF + p);
    unsigned short h, l;
    split_bf16(val, h, l);
    Ch[o] = h; Cl[o] = l;
}

// ---- MFMA GEMMs: 2-phase prefetch pipeline + swizzled LDS ---------------
// Swizzle (rule 21): linear gload_lds dest + pre-swizzled GLOBAL source +
// same-XOR read. Conflict-free ds_read_b128 (verified r1: 1.93M -> 0).
// Pipeline: stage chunk t+1, ds_read+MFMA chunk t, one syncthreads/iter.
#define GEMM_BODY(Ahi_, Alo_, Bhi_, Blo_, XARR_, XBASE_, BMASK_)                       \
    __shared__ short As_h[2][128][32];                                                 \
    __shared__ short As_l[2][128][32];                                                 \
    __shared__ short Bs_h[2][128][32];                                                 \
    __shared__ short Bs_l[2][128][32];                                                 \
    const int tid  = threadIdx.x;                                                      \
    const int lane = tid & 63;                                                         \
    const int wave = tid >> 6;                                                         \
    const int wr   = wave >> 1;                                                        \
    const int wc   = wave & 1;                                                         \
    const int row0 = blockIdx.y * 128;                                                 \
    const int col0 = blockIdx.x * 128;                                                 \
    int list[16]; int nch = 0;                                                         \
    {                                                                                  \
        float xmn = XARR_[XBASE_];                                                     \
        float xmx = XARR_[(XBASE_) + 127];                                             \
        int mask = 0;                                                                  \
        const int off_[5] = {0, 17, 50, 115, 244};                                     \
        _Pragma("unroll")                                                              \
        for (int l = 0; l < 5; ++l) {                                                  \
            int s_ = 8 << l;                                                           \
            int clo = off_[l] + s_ + (int)floorf(s_ * xmn - 12.5f);                    \
            int chi = off_[l] + s_ + (int)ceilf (s_ * xmx + 12.5f);                    \
            if (clo < off_[l]) clo = off_[l];                                          \
            if (chi > off_[l] + 2 * s_) chi = off_[l] + 2 * s_;                        \
            for (int c = clo >> 5; c <= (chi >> 5); ++c) mask |= 1 << c;               \
        }                                                                              \
        mask &= (BMASK_);                                                              \
        for (int c = 0; c < 16; ++c) if ((mask >> c) & 1) list[nch++] = c;             \
    }                                                                                  \
    f32x4 acc[4][4];                                                                   \
    _Pragma("unroll")                                                                  \
    for (int i = 0; i < 4; ++i)                                                        \
        _Pragma("unroll")                                                              \
        for (int j = 0; j < 4; ++j) acc[i][j] = (f32x4){0.f, 0.f, 0.f, 0.f};           \
    const int srow = lane >> 2;                                                        \
    const int scol = ((lane & 3) ^ ((lane >> 3) & 3)) * 8;  /* pre-swizzled source */  \
    auto stage_ = [&](int bb, int k0) {                                                \
        _Pragma("unroll")                                                              \
        for (int s = 0; s < 2; ++s) {                                                  \
            const int rseg = wave * 32 + s * 16;                                       \
            const size_t ga = (size_t)(row0 + rseg + srow) * KP + k0 + scol;           \
            const size_t gb = (size_t)(col0 + rseg + srow) * KP + k0 + scol;           \
            __builtin_amdgcn_global_load_lds(GLB(Ahi_ + ga), LDS(&As_h[bb][rseg][0]), 16, 0, 0); \
            __builtin_amdgcn_global_load_lds(GLB(Alo_ + ga), LDS(&As_l[bb][rseg][0]), 16, 0, 0); \
            __builtin_amdgcn_global_load_lds(GLB(Bhi_ + gb), LDS(&Bs_h[bb][rseg][0]), 16, 0, 0); \
            __builtin_amdgcn_global_load_lds(GLB(Blo_ + gb), LDS(&Bs_l[bb][rseg][0]), 16, 0, 0); \
        }                                                                              \
    };                                                                                 \
    const int kbsw = 8 * ((lane >> 4) ^ ((lane >> 1) & 3)); /* swizzled read slot */   \
    if (nch > 0) stage_(0, list[0] * 32);                                              \
    __syncthreads();                                                                   \
    for (int ic = 0; ic < nch; ++ic) {                                                 \
        const int cb = ic & 1;                                                         \
        if (ic + 1 < nch) stage_(cb ^ 1, list[ic + 1] * 32);                           \
        short8 ah[4], al[4], bh[4], bl[4];                                             \
        _Pragma("unroll")                                                              \
        for (int mb = 0; mb < 4; ++mb) {                                               \
            const int rr = wr * 64 + mb * 16 + (lane & 15);                            \
            ah[mb] = *(const short8*)&As_h[cb][rr][kbsw];                              \
            al[mb] = *(const short8*)&As_l[cb][rr][kbsw];                              \
        }                                                                              \
        _Pragma("unroll")                                                              \
        for (int nb = 0; nb < 4; ++nb) {                                               \
            const int cc = wc * 64 + nb * 16 + (lane & 15);                            \
            bh[nb] = *(const short8*)&Bs_h[cb][cc][kbsw];                              \
            bl[nb] = *(const short8*)&Bs_l[cb][cc][kbsw];                              \
        }                                                                              \
        _Pragma("unroll")                                                              \
        for (int mb = 0; mb < 4; ++mb)                                                 \
            _Pragma("unroll")                                                          \
            for (int nb = 0; nb < 4; ++nb) {                                           \
                acc[mb][nb] = __builtin_amdgcn_mfma_f32_16x16x32_bf16(ah[mb], bh[nb], acc[mb][nb], 0, 0, 0); \
                acc[mb][nb] = __builtin_amdgcn_mfma_f32_16x16x32_bf16(ah[mb], bl[nb], acc[mb][nb], 0, 0, 0); \
                acc[mb][nb] = __builtin_amdgcn_mfma_f32_16x16x32_bf16(al[mb], bh[nb], acc[mb][nb], 0, 0, 0); \
            }                                                                          \
        __syncthreads();                                                               \
    }                                                                                  \
    const int orow = (lane >> 4) * 4;                                                  \
    const int ocol = lane & 15;

// gemm2: out = U x PhiR^T, fp32 out; B-side (xr) k-sparsity from col-tile.
__global__ __launch_bounds__(256) void gemm_mfma_f32out(const short* __restrict__ Ahi,
                                                        const short* __restrict__ Alo,
                                                        const short* __restrict__ Bhi,
                                                        const short* __restrict__ Blo,
                                                        const float* __restrict__ xr,
                                                        float* __restrict__ out) {
    GEMM_BODY(Ahi, Alo, Bhi, Blo, xr, blockIdx.x * 128, 0xFFFF)
    #pragma unroll
    for (int mb = 0; mb < 4; ++mb)
        #pragma unroll
        for (int nb = 0; nb < 4; ++nb) {
            const int col = col0 + wc * 64 + nb * 16 + ocol;
            #pragma unroll
            for (int reg = 0; reg < 4; ++reg) {
                const int row = row0 + wr * 64 + mb * 16 + orow + reg;
                out[(size_t)row * NN + col] = acc[mb][nb][reg];
            }
        }
}

// gemm1: U = PhiC x C^T, split-bf16 out; A-side (xc) sparsity AND static
// block-diagonal B mask by col-tile.
__global__ __launch_bounds__(256) void gemm_mfma_splitout(const short* __restrict__ Ahi,
                                                          const short* __restrict__ Alo,
                                                          const short* __restrict__ Bhi,
                                                          const short* __restrict__ Blo,
                                                          const float* __restrict__ xc,
                                                          unsigned short* __restrict__ Oh,
                                                          unsigned short* __restrict__ Ol) {
    const int bmask_tab[4] = {0x00FF, 0xFFF8, 0xFF80, 0xFF80};
    const int bm = bmask_tab[blockIdx.x];
    GEMM_BODY(Ahi, Alo, Bhi, Blo, xc, blockIdx.y * 128, bm)
    #pragma unroll
    for (int mb = 0; mb < 4; ++mb)
        #pragma unroll
        for (int nb = 0; nb < 4; ++nb) {
            const int col = col0 + wc * 64 + nb * 16 + ocol;
            #pragma unroll
            for (int reg = 0; reg < 4; ++reg) {
                const int row = row0 + wr * 64 + mb * 16 + orow + reg;
                unsigned short h, l;
                split_bf16(acc[mb][nb][reg], h, l);
                Oh[(size_t)row * KP + col] = h;
                Ol[(size_t)row * KP + col] = l;
            }
        }
}

extern "C" void kernel_launch(void* const* d_in, const int* in_sizes, int n_in,
                              void* d_out, int out_size, void* d_ws, size_t ws_size,
                              hipStream_t stream) {
    const float* img = (const float*)d_in[0];
    const float* xc  = (const float*)d_in[1];
    const float* xr  = (const float*)d_in[2];
    float* out = (float*)d_out;

    const size_t M2 = (size_t)NN * KP;
    // ws: PCh|PCl|PRh|PRl|Uh|Ul (6 x 4MB bf16) | Usm(1MB) | (unused 1MB) | Ch|Cl(1MB) | idx
    unsigned short* PCh = (unsigned short*)d_ws;
    unsigned short* PCl = PCh + M2;
    unsigned short* PRh = PCl + M2;
    unsigned short* PRl = PRh + M2;
    unsigned short* Uh  = PRl + M2;
    unsigned short* Ul  = Uh + M2;
    float* Usm = (float*)(Ul + M2);
    float* CdT = Usm + (size_t)KP * KP;          // no longer written (kept for layout)
    unsigned short* Ch = (unsigned short*)(CdT + (size_t)KP * KP);
    unsigned short* Cl = Ch + (size_t)KP * KP;
    int* idxAll = (int*)(Cl + (size_t)KP * KP);

    // 1: prep (nearest + split phi tables + zero Ch/Cl)
    fused_pre<<<dim3(2058), 256, 0, stream>>>(xc, xr, PCh, PCl, PRh, PRl, Ch, idxAll);

    // 2-6: level chain, folded build+update (one block per column t).
    // 9 launches -> 5; CdT eliminated (column lives in LDS).
    fold_k<17, 0>   <<<dim3(17),  256, 0, stream>>>(img, idxAll, Usm, PRh, PRl, PCh, PCl, Ch, Cl);
    fold_k<33, 17>  <<<dim3(33),  256, 0, stream>>>(img, idxAll, Usm, PRh, PRl, PCh, PCl, Ch, Cl);
    fold_k<65, 50>  <<<dim3(65),  256, 0, stream>>>(img, idxAll, Usm, PRh, PRl, PCh, PCl, Ch, Cl);
    fold_k<129, 115><<<dim3(129), 256, 0, stream>>>(img, idxAll, Usm, PRh, PRl, PCh, PCl, Ch, Cl);
    build_last      <<<dim3(259), 256, 0, stream>>>(img, idxAll, Usm, PRh, PRl, Ch, Cl);

    // 7: gemm1  U = PhiC x C^T (split-bf16 out)
    gemm_mfma_splitout<<<dim3(KP / 128, NN / 128), 256, 0, stream>>>(
        (const short*)PCh, (const short*)PCl, (const short*)Ch, (const short*)Cl, xc, Uh, Ul);
    // 8: gemm2  out = U x PhiR^T
    gemm_mfma_f32out<<<dim3(NN / 128, NN / 128), 256, 0, stream>>>(
        (const short*)Uh, (const short*)Ul, (const short*)PRh, (const short*)PRl, xr, out);
}